// Round 20
// baseline (78.918 us; speedup 1.0000x reference)
//
#include <hip/hip_runtime.h>
#include <float.h>

// Chamfer distance, fp32, N=M=16384 — R20: rotated LDS sweep pipeline.
//
// R19 (setprio) exactly null. R16's decomposition stands: sweep = 14us =
// SERIAL sum of its pipes (MFMA 6.8 + min3 3.4 + DS 5.1), no overlap. Root
// cause theory: loop order ds_read -> MFMA -> min3 exposes full ~120cy LDS
// latency every iteration (MFMA waits on loads issued cycles earlier); all
// 16 waves/CU expose it in lockstep. R20 rotates: MFMA on the RESIDENT
// pair first, then issue NEXT pair's ds_reads, then 32 min3 (~128cy issue)
// covering DS + MFMA-result latency. Prior prefetch nulls (R11/R14) were
// in the global-read regime where this wasn't the bottleneck. Liveness
// ~115 VGPR <= 128 cap (d consumed in-iteration, one b-pair in flight).
//
// Math (absmax 0.0, R7-R19): d = u.t + |t|^2 + |q|^2, u=-2q, 2-level bf16
// split, full product expansion in K=14 of 16:
//   k:      0..2     3..5     6..7+8   9..11    12 13
//   A:    uh(xyz)  ul(xyz)  uh(xyz)  ul(xyz)    1  1
//   B:    th(xyz)  th(xyz)  tl(xyz)  tl(xyz)   wh wl
// Layouts (guide §3, m74/m101): A row=lane&31, k=8*(lane>>5)+j; B col=
// lane&31; D col=lane&31, row=(reg&3)+8*(reg>>2)+4*(lane>>5).

#define NPTS 16384
constexpr int QPB   = 512;                // queries per block (64 per wave)
constexpr int NQB   = NPTS / QPB;         // 32 query-blocks per direction
constexpr int TPC   = 2048;               // targets per chunk
constexpr int NTC   = NPTS / TPC;         // 8 target chunks
constexpr int FPC   = TPC / 32;           // 64 frags per chunk (64KB LDS)
constexpr int FRAG_SHORTS = 512;          // 64 lane-slots x 8 bf16 = 1KB/frag

typedef float  f32x4  __attribute__((ext_vector_type(4)));
typedef float  f32x16 __attribute__((ext_vector_type(16)));
typedef short  bf16x8 __attribute__((ext_vector_type(8)));

__device__ inline ushort bf16rne(float f) {
    uint u = __float_as_uint(f);
    u += 0x7fff + ((u >> 16) & 1);        // round-to-nearest-even
    return (ushort)(u >> 16);
}
__device__ inline float bf2f(ushort h) { return __uint_as_float(((uint)h) << 16); }

__global__ __launch_bounds__(512, 2) void cd_main(const float* __restrict__ gt,
                                                  const float* __restrict__ gen,
                                                  float* __restrict__ part2,
                                                  float* __restrict__ out) {
    const int tc  = blockIdx.y & (NTC - 1);        // target chunk 0..7
    const int dir = blockIdx.y >> 3;               // 0: gt->gen, 1: gen->gt
    const float* __restrict__ Q = dir ? gen : gt;
    const float* __restrict__ T = dir ? gt : gen;  // opposite set

    if (blockIdx.x == 0 && blockIdx.y == 0 && threadIdx.x == 0)
        out[0] = 0.0f;                             // safe: finish launches after

    __shared__ short FRsh[FPC * FRAG_SHORTS];      // 64 KB: B-frags of chunk

    const int tid  = threadIdx.x;
    const int lane = tid & 63;
    const int wave = __builtin_amdgcn_readfirstlane(tid >> 6);

    // ---- Fused split: stage this chunk's 2048 raw points -> B-frag LDS.
    //      Thread tid: points tid*4..tid*4+3 via 3 coalesced float4 loads. ----
    {
        const float* src = T + (size_t)tc * TPC * 3 + tid * 12;
        const f32x4 v0 = *(const f32x4*)(src + 0);
        const f32x4 v1 = *(const f32x4*)(src + 4);
        const f32x4 v2 = *(const f32x4*)(src + 8);
        const float px[4] = {v0.x, v0.w, v1.z, v2.y};
        const float py[4] = {v0.y, v1.x, v1.w, v2.z};
        const float pz[4] = {v0.z, v1.y, v2.x, v2.w};
        #pragma unroll
        for (int j = 0; j < 4; ++j) {
            const int p = tid * 4 + j;             // point within chunk
            const float x = px[j], y = py[j], z = pz[j];
            const ushort hx = bf16rne(x), hy = bf16rne(y), hz = bf16rne(z);
            const ushort lx = bf16rne(x - bf2f(hx));
            const ushort ly = bf16rne(y - bf2f(hy));
            const ushort lz = bf16rne(z - bf2f(hz));
            const float w = fmaf(x, x, fmaf(y, y, z * z));
            const ushort wh = bf16rne(w), wl = bf16rne(w - bf2f(wh));
            short* fb = FRsh + (p >> 5) * FRAG_SHORTS + (p & 31) * 8;
            *(bf16x8*)fb =
                (bf16x8){(short)hx, (short)hy, (short)hz, (short)hx,
                         (short)hy, (short)hz, (short)lx, (short)ly};
            *(bf16x8*)(fb + 256) =                 // k-group 1: lane 32+col
                (bf16x8){(short)lz, (short)lx, (short)ly, (short)lz,
                         (short)wh, (short)wl, (short)0, (short)0};
        }
    }

    // ---- 2 A-frags per wave (each wave owns 64 distinct queries). ----
    const int arow = lane & 31, kg = lane >> 5;
    const int qw = blockIdx.x * QPB + wave * 64;   // this wave's query base
    bf16x8 a[2];
    #pragma unroll
    for (int f = 0; f < 2; ++f) {
        const int q = qw + f * 32 + arow;
        const float x = Q[3 * q + 0], y = Q[3 * q + 1], z = Q[3 * q + 2];
        const float ux = -2.f * x, uy = -2.f * y, uz = -2.f * z;
        const ushort hx = bf16rne(ux), hy = bf16rne(uy), hz = bf16rne(uz);
        const ushort lx = bf16rne(ux - bf2f(hx));
        const ushort ly = bf16rne(uy - bf2f(hy));
        const ushort lz = bf16rne(uz - bf2f(hz));
        if (kg == 0)
            a[f] = (bf16x8){(short)hx, (short)hy, (short)hz, (short)lx,
                            (short)ly, (short)lz, (short)hx, (short)hy};
        else
            a[f] = (bf16x8){(short)hz, (short)lx, (short)ly, (short)lz,
                            (short)0x3f80, (short)0x3f80, (short)0, (short)0};
    }

    f32x16 mm0 = (f32x16)(FLT_MAX), mm1 = (f32x16)(FLT_MAX);
    const f32x16 zc = (f32x16)(0.f);

    __syncthreads();                               // chunk staged

    // ---- Rotated sweep: MFMA on resident pair -> issue next pair's
    //      ds_reads -> min3 block covers DS + MFMA latency. ----
    const short* rb = FRsh + lane * 8;
    bf16x8 b0 = *(const bf16x8*)(rb);
    bf16x8 b1 = *(const bf16x8*)(rb + FRAG_SHORTS);
    for (int f2 = 0; f2 < FPC; f2 += 2) {
        const f32x16 d00 = __builtin_amdgcn_mfma_f32_32x32x16_bf16(a[0], b0, zc, 0, 0, 0);
        const f32x16 d01 = __builtin_amdgcn_mfma_f32_32x32x16_bf16(a[0], b1, zc, 0, 0, 0);
        const f32x16 d10 = __builtin_amdgcn_mfma_f32_32x32x16_bf16(a[1], b0, zc, 0, 0, 0);
        const f32x16 d11 = __builtin_amdgcn_mfma_f32_32x32x16_bf16(a[1], b1, zc, 0, 0, 0);
        const int nf = (f2 + 2) & (FPC - 1);       // last iter: harmless wrap
        b0 = *(const bf16x8*)(rb + nf * FRAG_SHORTS);
        b1 = *(const bf16x8*)(rb + (nf + 1) * FRAG_SHORTS);
        #pragma unroll
        for (int i = 0; i < 16; ++i) {
            mm0[i] = fminf(fminf(d00[i], d01[i]), mm0[i]);   // -> v_min3_f32
            mm1[i] = fminf(fminf(d10[i], d11[i]), mm1[i]);
        }
    }

    // ---- Cross-lane min over the 32 target-cols; write partials direct. ----
    float* pd = part2 + (size_t)blockIdx.y * NPTS + qw;   // [dir*8+tc][q]
    #pragma unroll
    for (int i = 0; i < 16; ++i) {
        float v0 = mm0[i], v1 = mm1[i];
        #pragma unroll
        for (int off = 1; off <= 16; off <<= 1) {
            v0 = fminf(v0, __shfl_xor(v0, off, 64));
            v1 = fminf(v1, __shfl_xor(v1, off, 64));
        }
        const int row = (i & 3) + 8 * (i >> 2) + 4 * kg;
        if ((lane & 31) == 0) {
            pd[row]      = v0;                     // frag 0: query qw+row
            pd[32 + row] = v1;                     // frag 1: query qw+32+row
        }
    }
}

// min over the 8 chunk-partials, add |q|^2, global sum.
__global__ __launch_bounds__(512) void cd_finish(const float* __restrict__ gt,
                                                 const float* __restrict__ gen,
                                                 const float* __restrict__ part2,
                                                 float* __restrict__ out) {
    const int t   = blockIdx.x * 512 + threadIdx.x;   // 0..32767
    const int dir = t >> 14;
    const int q   = t & (NPTS - 1);
    const float* __restrict__ Q = dir ? gen : gt;

    float m = FLT_MAX;
    #pragma unroll
    for (int tc = 0; tc < NTC; ++tc)
        m = fminf(m, part2[(size_t)(dir * NTC + tc) * NPTS + q]);
    const float x = Q[3 * q + 0], y = Q[3 * q + 1], z = Q[3 * q + 2];
    float v = m + fmaf(x, x, fmaf(y, y, z * z));

    #pragma unroll
    for (int off = 32; off > 0; off >>= 1) v += __shfl_down(v, off, 64);
    __shared__ float ws[8];
    const int lane = threadIdx.x & 63, w = threadIdx.x >> 6;
    if (lane == 0) ws[w] = v;
    __syncthreads();
    if (threadIdx.x == 0) {
        float s = 0.0f;
        #pragma unroll
        for (int i = 0; i < 8; ++i) s += ws[i];
        atomicAdd(out, s * (1.0f / (float)NPTS));
    }
}

extern "C" void kernel_launch(void* const* d_in, const int* in_sizes, int n_in,
                              void* d_out, int out_size, void* d_ws, size_t ws_size,
                              hipStream_t stream) {
    const float* gt  = (const float*)d_in[0];
    const float* gen = (const float*)d_in[1];
    float* part2     = (float*)d_ws;               // 16 x 16384 f32 = 1 MB
    float* out       = (float*)d_out;

    dim3 grid(NQB, NTC * 2);                       // 32 x 16 = 512 blocks
    cd_main<<<grid, 512, 0, stream>>>(gt, gen, part2, out);
    cd_finish<<<64, 512, 0, stream>>>(gt, gen, part2, out);
}